// Round 1
// baseline (747.360 us; speedup 1.0000x reference)
//
#include <hip/hip_runtime.h>

// LayoutLM w/ visual features — fp32 baseline.
// B=64 S=512 H=768 R=256 VD=256 NC=9
// Restructured: vis-proj folded into fuse GEMM via Weq = W_proj @ W_fuse[768:],
// masked mean-pool done sparsely (mask ~0.2% dense).
// ws layout (floats): text[16384*768] | fused[16384*768] | Weq[256*768] | beq[768]
//                     h[16384*512] aliases text (text dead after fuse GEMM). ~102 MB.

#define Bb 64
#define Ss 512
#define Hh 768
#define Rr 256
#define VDd 256
#define NCc 9

// ---------------- Weq / beq precompute ----------------
// grid 257 blocks x 768 threads. Block m<256: Weq row m = W_proj[m,:] @ Wf_v.
// Block 256: beq = b_fuse + b_proj @ Wf_v.  Wf_v = W_fuse rows 768..1535.
__global__ __launch_bounds__(768) void weq_beq_kernel(
    const float* __restrict__ Wp, const float* __restrict__ bp,
    const float* __restrict__ Wf, const float* __restrict__ bf,
    float* __restrict__ Weq, float* __restrict__ beq)
{
    int n = threadIdx.x;
    int m = blockIdx.x;
    const float* Wfv = Wf + 768 * 768 + n;   // column n of Wf_v
    float acc = 0.f;
    if (m < 256) {
        const float* a = Wp + m * 768;
        #pragma unroll 4
        for (int k = 0; k < 768; ++k) acc += a[k] * Wfv[(size_t)k * 768];
        Weq[m * 768 + n] = acc;
    } else {
        #pragma unroll 4
        for (int k = 0; k < 768; ++k) acc += bp[k] * Wfv[(size_t)k * 768];
        beq[n] = bf[n] + acc;
    }
}

// ---------------- sparse masked mean pool ----------------
// grid = B*R blocks, 256 threads. Deterministic ballot-compaction of matched
// token indices, then cooperative accumulation of seq rows (H=768 = 3*256).
__global__ __launch_bounds__(256) void pool_kernel(
    const float* __restrict__ seq,   // [B,S,H]
    const float* __restrict__ roi,   // [B,R,4]
    const int*   __restrict__ bbox,  // [B,S,4] (int32)
    const int*   __restrict__ amask, // [B,S]
    float* __restrict__ text)        // [B*R,H]
{
    int br = blockIdx.x;
    int b  = br >> 8;               // R=256
    int tid = threadIdx.x;
    int wave = tid >> 6, lane = tid & 63;

    float4 rb = reinterpret_cast<const float4*>(roi)[br];

    __shared__ unsigned long long wm[8];
    __shared__ int s_idx[Ss];

    const int4* bb4 = reinterpret_cast<const int4*>(bbox) + (size_t)b * Ss;
    const int*  am  = amask + (size_t)b * Ss;

    for (int it = 0; it < 2; ++it) {
        int s = it * 256 + tid;
        bool pred = false;
        if (s >= 1 && am[s] == 1) {
            int4 tb = bb4[s];
            pred = ((float)tb.x >= rb.x) && ((float)tb.z <= rb.z) &&
                   ((float)tb.y >= rb.y) && ((float)tb.w <= rb.w);
        }
        unsigned long long mk = __ballot(pred);
        if (lane == 0) wm[it * 4 + wave] = mk;
    }
    __syncthreads();

    // exclusive prefix over the 8 chunk masks (every thread computes it)
    int pre[8]; int tot = 0;
    #pragma unroll
    for (int c = 0; c < 8; ++c) { pre[c] = tot; tot += __popcll(wm[c]); }

    #pragma unroll
    for (int it = 0; it < 2; ++it) {
        int c = it * 4 + wave;
        unsigned long long mk = wm[c];
        if ((mk >> lane) & 1ull) {
            int pos = pre[c] + __popcll(mk & ((1ull << lane) - 1ull));
            s_idx[pos] = c * 64 + lane;
        }
    }
    __syncthreads();

    float a0 = 0.f, a1 = 0.f, a2 = 0.f;
    for (int i = 0; i < tot; ++i) {
        const float* row = seq + ((size_t)b * Ss + s_idx[i]) * Hh;
        a0 += row[tid];
        a1 += row[tid + 256];
        a2 += row[tid + 512];
    }
    float inv = 1.f / fmaxf((float)tot, 1.f);
    float* o = text + (size_t)br * Hh;
    o[tid]       = a0 * inv;
    o[tid + 256] = a1 * inv;
    o[tid + 512] = a2 * inv;
}

// ---------------- fp32 GEMM: C = act(A1@W1 + A2@W2 + bias) ----------------
// 128x128 tile, BK=16, 256 threads, 8x8 microtile (split 4+4 fragments).
// grid = (N/128, M/128). A row-major [M,lda], W row-major [K,ldw].
__global__ __launch_bounds__(256) void gemm128(
    const float* __restrict__ A1, int lda1, int K1,
    const float* __restrict__ W1, int ldw1,
    const float* __restrict__ A2, int lda2, int K2,
    const float* __restrict__ W2, int ldw2,
    const float* __restrict__ bias, int relu,
    float* __restrict__ C, int ldc)
{
    __shared__ float As[16][128];   // [k][m]
    __shared__ float Ws[16][128];   // [k][n]

    int tid = threadIdx.x;
    int tx = tid & 15, ty = tid >> 4;
    int m0 = blockIdx.y * 128;
    int n0 = blockIdx.x * 128;

    int ar_ = tid >> 2;          // A row 0..63 (and +64)
    int ak_ = (tid & 3) * 4;     // A k offset (float4)
    int wr_ = tid >> 5;          // W k row 0..7 (and +8)
    int wq_ = (tid & 31) * 4;    // W n offset (float4)

    float acc[8][8] = {};

    for (int seg = 0; seg < 2; ++seg) {
        const float* A = seg ? A2 : A1;
        if (A == nullptr) break;
        int lda = seg ? lda2 : lda1;
        int Klen = seg ? K2 : K1;
        const float* W = seg ? W2 : W1;
        int ldw = seg ? ldw2 : ldw1;

        const float* Ab0 = A + (size_t)(m0 + ar_) * lda + ak_;
        const float* Ab1 = A + (size_t)(m0 + 64 + ar_) * lda + ak_;
        const float* Wb0 = W + (size_t)wr_ * ldw + n0 + wq_;
        const float* Wb1 = W + (size_t)(wr_ + 8) * ldw + n0 + wq_;

        for (int k0 = 0; k0 < Klen; k0 += 16) {
            float4 av0 = *(const float4*)(Ab0 + k0);
            float4 av1 = *(const float4*)(Ab1 + k0);
            float4 wv0 = *(const float4*)(Wb0 + (size_t)k0 * ldw);
            float4 wv1 = *(const float4*)(Wb1 + (size_t)k0 * ldw);

            __syncthreads();
            As[ak_ + 0][ar_] = av0.x;  As[ak_ + 1][ar_] = av0.y;
            As[ak_ + 2][ar_] = av0.z;  As[ak_ + 3][ar_] = av0.w;
            As[ak_ + 0][64 + ar_] = av1.x;  As[ak_ + 1][64 + ar_] = av1.y;
            As[ak_ + 2][64 + ar_] = av1.z;  As[ak_ + 3][64 + ar_] = av1.w;
            *(float4*)&Ws[wr_][wq_]     = wv0;
            *(float4*)&Ws[wr_ + 8][wq_] = wv1;
            __syncthreads();

            #pragma unroll
            for (int k = 0; k < 16; ++k) {
                float4 a0 = *(const float4*)&As[k][ty * 4];
                float4 a1 = *(const float4*)&As[k][64 + ty * 4];
                float4 b0 = *(const float4*)&Ws[k][tx * 4];
                float4 b1 = *(const float4*)&Ws[k][64 + tx * 4];
                float ar[8] = {a0.x, a0.y, a0.z, a0.w, a1.x, a1.y, a1.z, a1.w};
                float br[8] = {b0.x, b0.y, b0.z, b0.w, b1.x, b1.y, b1.z, b1.w};
                #pragma unroll
                for (int j = 0; j < 8; ++j)
                    #pragma unroll
                    for (int i = 0; i < 8; ++i)
                        acc[j][i] += ar[j] * br[i];
            }
        }
    }

    float bv[8];
    #pragma unroll
    for (int i = 0; i < 4; ++i) {
        bv[i]     = bias ? bias[n0 + tx * 4 + i]      : 0.f;
        bv[4 + i] = bias ? bias[n0 + 64 + tx * 4 + i] : 0.f;
    }
    #pragma unroll
    for (int j = 0; j < 8; ++j) {
        int mrow = m0 + ((j < 4) ? (ty * 4 + j) : (64 + ty * 4 + j - 4));
        float o[8];
        #pragma unroll
        for (int i = 0; i < 8; ++i) {
            float v = acc[j][i] + bv[i];
            o[i] = relu ? fmaxf(v, 0.f) : v;
        }
        *(float4*)(C + (size_t)mrow * ldc + n0 + tx * 4)      = make_float4(o[0], o[1], o[2], o[3]);
        *(float4*)(C + (size_t)mrow * ldc + n0 + 64 + tx * 4) = make_float4(o[4], o[5], o[6], o[7]);
    }
}

// ---------------- logits: out = h @ W2 + b2, K=512, N=9 ----------------
// one wave per row; lane holds k = lane + 64*j (stride-64 slices so LDS W2
// reads are stride-9 (coprime with 32 banks -> conflict-free) and h loads
// are coalesced per j.
__global__ __launch_bounds__(256) void logits_kernel(
    const float* __restrict__ h, const float* __restrict__ W2,
    const float* __restrict__ b2, float* __restrict__ out)
{
    __shared__ float w2s[512 * NCc];
    for (int i = threadIdx.x; i < 512 * NCc; i += 256) w2s[i] = W2[i];
    __syncthreads();

    int wave = threadIdx.x >> 6, lane = threadIdx.x & 63;
    int row = blockIdx.x * 4 + wave;
    const float* hr = h + (size_t)row * 512;

    float p[NCc] = {};
    #pragma unroll
    for (int j = 0; j < 8; ++j) {
        int k = lane + 64 * j;
        float hv = hr[k];
        const float* wrow = &w2s[k * NCc];
        #pragma unroll
        for (int n = 0; n < NCc; ++n) p[n] += hv * wrow[n];
    }
    #pragma unroll
    for (int off = 32; off > 0; off >>= 1) {
        #pragma unroll
        for (int n = 0; n < NCc; ++n) p[n] += __shfl_down(p[n], off);
    }
    if (lane == 0) {
        float* orow = out + (size_t)row * NCc;
        #pragma unroll
        for (int n = 0; n < NCc; ++n) orow[n] = p[n] + b2[n];
    }
}

extern "C" void kernel_launch(void* const* d_in, const int* in_sizes, int n_in,
                              void* d_out, int out_size, void* d_ws, size_t ws_size,
                              hipStream_t stream)
{
    const float* seq   = (const float*)d_in[0];   // [B,S,H]
    const float* feats = (const float*)d_in[1];   // [B,R,VD]
    const float* roi   = (const float*)d_in[2];   // [B,R,4]
    const int*   bbox  = (const int*)d_in[3];     // [B,S,4]
    const int*   amask = (const int*)d_in[4];     // [B,S]
    const float* Wp = (const float*)d_in[5];      // [256,768]
    const float* bp = (const float*)d_in[6];      // [768]
    const float* Wf = (const float*)d_in[7];      // [1536,768]
    const float* bf = (const float*)d_in[8];      // [768]
    const float* W1 = (const float*)d_in[9];      // [768,512]
    const float* b1 = (const float*)d_in[10];     // [512]
    const float* W2 = (const float*)d_in[11];     // [512,9]
    const float* b2 = (const float*)d_in[12];     // [9]
    float* out = (float*)d_out;

    float* ws    = (float*)d_ws;
    float* text  = ws;                          // [16384,768]
    float* fused = ws + (size_t)16384 * 768;    // [16384,768]
    float* hbuf  = ws;                          // [16384,512] aliases text (dead)
    float* Weq   = ws + (size_t)2 * 16384 * 768;// [256,768]
    float* beq   = Weq + 256 * 768;             // [768]

    weq_beq_kernel<<<257, 768, 0, stream>>>(Wp, bp, Wf, bf, Weq, beq);
    pool_kernel<<<Bb * Rr, 256, 0, stream>>>(seq, roi, bbox, amask, text);
    // fused = relu(text @ Wf[0:768] + feats @ Weq + beq)
    gemm128<<<dim3(Hh / 128, (Bb * Rr) / 128), 256, 0, stream>>>(
        text, Hh, Hh, Wf, Hh,
        feats, VDd, VDd, Weq, Hh,
        beq, 1, fused, Hh);
    // h = relu(fused @ W_h1 + b_h1)
    gemm128<<<dim3(512 / 128, (Bb * Rr) / 128), 256, 0, stream>>>(
        fused, Hh, Hh, W1, 512,
        nullptr, 0, 0, nullptr, 0,
        b1, 1, hbuf, 512);
    // logits = h @ W_h2 + b_h2
    logits_kernel<<<(Bb * Rr) / 4, 256, 0, stream>>>(hbuf, W2, b2, out);
}

// Round 8
// 484.044 us; speedup vs baseline: 1.5440x; 1.5440x over previous
//
#include <hip/hip_runtime.h>
#include <hip/hip_bf16.h>

// LayoutLM w/ visual features — split-bf16 MFMA version.
// B=64 S=512 H=768 R=256 VD=256 NC=9
// fuse GEMM: [16384,1024]@[1024,768] (A = text|feats concat, B = Wf_t|Weq concat)
// h1  GEMM: [16384,768]@[768,512]
// Both run as 3-term split-bf16 MFMA (Ah*Bh + Ah*Bl + Al*Bh), fp32 accum.
//
// ws layout (bytes):
//   A_hi   [16384][1024] bf16   @ 0          (33,554,432)   } h[16384][512] f32
//   A_lo   [16384][1024] bf16   @ 33,554,432 (33,554,432)   }   aliases A_hi after fuse
//   fus_hi [16384][768] bf16    @ 67,108,864 (25,165,824)
//   fus_lo [16384][768] bf16    @ 92,274,688 (25,165,824)
//   Bf_hi  [768][1024] bf16     @117,440,512 ( 1,572,864)
//   Bf_lo  [768][1024] bf16     @119,013,376 ( 1,572,864)
//   B1_hi  [512][768] bf16      @120,586,240 (   786,432)
//   B1_lo  [512][768] bf16      @121,372,672 (   786,432)
//   Weq f32 [256][768]          @122,159,104 (   786,432)
//   beq f32 [768]               @122,945,536 (     3,072)
// total ~123 MB.

#define Bb 64
#define Ss 512
#define Hh 768
#define Rr 256
#define VDd 256
#define NCc 9

typedef __attribute__((ext_vector_type(8))) short short8v;  // 8 bf16 = 4 VGPR
typedef __attribute__((ext_vector_type(4))) float f32x4;

__device__ __forceinline__ unsigned short f2bf(float v) {
    __hip_bfloat16 b = __float2bfloat16(v);
    return __builtin_bit_cast(unsigned short, b);
}
__device__ __forceinline__ float bf2f(unsigned short u) {
    return __bfloat162float(__builtin_bit_cast(__hip_bfloat16, u));
}

__device__ __forceinline__ void gll16(const void* g, void* l) {
    __builtin_amdgcn_global_load_lds(
        (const __attribute__((address_space(1))) void*)g,
        (__attribute__((address_space(3))) void*)l, 16, 0, 0);
}

// ---------------- Weq / beq precompute (fp32) ----------------
__global__ __launch_bounds__(768) void weq_beq_kernel(
    const float* __restrict__ Wp, const float* __restrict__ bp,
    const float* __restrict__ Wf, const float* __restrict__ bf,
    float* __restrict__ Weq, float* __restrict__ beq)
{
    int n = threadIdx.x;
    int m = blockIdx.x;
    const float* Wfv = Wf + 768 * 768 + n;   // column n of Wf_v
    float acc = 0.f;
    if (m < 256) {
        const float* a = Wp + m * 768;
        #pragma unroll 4
        for (int k = 0; k < 768; ++k) acc += a[k] * Wfv[(size_t)k * 768];
        Weq[m * 768 + n] = acc;
    } else {
        #pragma unroll 4
        for (int k = 0; k < 768; ++k) acc += bp[k] * Wfv[(size_t)k * 768];
        beq[n] = bf[n] + acc;
    }
}

// ---------------- sparse masked mean pool -> bf16 hi/lo ----------------
__global__ __launch_bounds__(256) void pool_kernel(
    const float* __restrict__ seq,   // [B,S,H]
    const float* __restrict__ roi,   // [B,R,4]
    const int*   __restrict__ bbox,  // [B,S,4]
    const int*   __restrict__ amask, // [B,S]
    unsigned short* __restrict__ ah, // A_hi [16384][1024], cols 0..767
    unsigned short* __restrict__ al)
{
    int br = blockIdx.x;
    int b  = br >> 8;
    int tid = threadIdx.x;
    int wave = tid >> 6, lane = tid & 63;

    float4 rb = reinterpret_cast<const float4*>(roi)[br];

    __shared__ unsigned long long wm[8];
    __shared__ int s_idx[Ss];

    const int4* bb4 = reinterpret_cast<const int4*>(bbox) + (size_t)b * Ss;
    const int*  am  = amask + (size_t)b * Ss;

    for (int it = 0; it < 2; ++it) {
        int s = it * 256 + tid;
        bool pred = false;
        if (s >= 1 && am[s] == 1) {
            int4 tb = bb4[s];
            pred = ((float)tb.x >= rb.x) && ((float)tb.z <= rb.z) &&
                   ((float)tb.y >= rb.y) && ((float)tb.w <= rb.w);
        }
        unsigned long long mk = __ballot(pred);
        if (lane == 0) wm[it * 4 + wave] = mk;
    }
    __syncthreads();

    int pre[8]; int tot = 0;
    #pragma unroll
    for (int c = 0; c < 8; ++c) { pre[c] = tot; tot += __popcll(wm[c]); }

    #pragma unroll
    for (int it = 0; it < 2; ++it) {
        int c = it * 4 + wave;
        unsigned long long mk = wm[c];
        if ((mk >> lane) & 1ull) {
            int pos = pre[c] + __popcll(mk & ((1ull << lane) - 1ull));
            s_idx[pos] = c * 64 + lane;
        }
    }
    __syncthreads();

    float a0 = 0.f, a1 = 0.f, a2 = 0.f;
    for (int i = 0; i < tot; ++i) {
        const float* row = seq + ((size_t)b * Ss + s_idx[i]) * Hh;
        a0 += row[tid];
        a1 += row[tid + 256];
        a2 += row[tid + 512];
    }
    float inv = 1.f / fmaxf((float)tot, 1.f);
    a0 *= inv; a1 *= inv; a2 *= inv;

    size_t o = (size_t)br * 1024;
    unsigned short h0 = f2bf(a0), h1 = f2bf(a1), h2 = f2bf(a2);
    ah[o + tid]       = h0;  al[o + tid]       = f2bf(a0 - bf2f(h0));
    ah[o + tid + 256] = h1;  al[o + tid + 256] = f2bf(a1 - bf2f(h1));
    ah[o + tid + 512] = h2;  al[o + tid + 512] = f2bf(a2 - bf2f(h2));
}

// ---------------- feats -> A_cat cols 768..1023 (bf16 hi/lo) ----------------
__global__ __launch_bounds__(256) void feats_conv(
    const float* __restrict__ f, unsigned short* __restrict__ ah,
    unsigned short* __restrict__ al)
{
    int m = blockIdx.x, c = threadIdx.x;
    float v = f[(size_t)m * VDd + c];
    size_t o = (size_t)m * 1024 + 768 + c;
    unsigned short h = f2bf(v);
    ah[o] = h;
    al[o] = f2bf(v - bf2f(h));
}

// ---------------- transpose + split-convert: dst[n][co+k] = src[k][n] ----------------
// src fp32 [Ks][Ns]; grid (Ks/32, Ns/32), 256 thr.
__global__ __launch_bounds__(256) void tconv_kernel(
    const float* __restrict__ src, int Ns,
    unsigned short* __restrict__ dh, unsigned short* __restrict__ dl,
    int ldd, int co)
{
    __shared__ float t[32][33];
    int k0 = blockIdx.x * 32, n0 = blockIdx.y * 32;
    int tx = threadIdx.x & 31, ty = threadIdx.x >> 5;
    #pragma unroll
    for (int i = 0; i < 4; ++i)
        t[ty + i * 8][tx] = src[(size_t)(k0 + ty + i * 8) * Ns + n0 + tx];
    __syncthreads();
    #pragma unroll
    for (int i = 0; i < 4; ++i) {
        int n = n0 + ty + i * 8;
        int k = k0 + tx;
        float v = t[tx][ty + i * 8];
        size_t o = (size_t)n * ldd + co + k;
        unsigned short h = f2bf(v);
        dh[o] = h;
        dl[o] = f2bf(v - bf2f(h));
    }
}

// ---------------- split-bf16 MFMA GEMM ----------------
// C[M,N] = relu( (Ah+Al)[M,K] @ (Bh+Bl)[K,N] + bias ), 3-term expansion.
// A row-major [M][lda] bf16; B transposed [N][ldb] bf16 (Bt[n][k] = B[k][n]).
// 128x128 tile, BK=32, 256 thr (4 waves, 2x2 of 64x64), mfma 16x16x32.
// LDS: 4 tiles of [128 rows][32 bf16] = 8 KB each, XOR-swizzled chunks.
// epi=1: split-bf16 store to Ch/Cl; epi=0: fp32 store to Cf.
__global__ __launch_bounds__(256) void gemm_mfma(
    const unsigned short* __restrict__ Ah, const unsigned short* __restrict__ Al, int lda,
    const unsigned short* __restrict__ Bh, const unsigned short* __restrict__ Bl, int ldb,
    int K, const float* __restrict__ bias, int epi,
    unsigned short* __restrict__ Ch, unsigned short* __restrict__ Cl,
    float* __restrict__ Cf, int ldc)
{
    __shared__ __align__(16) unsigned char lds[32768];
    const int ATH = 0, ATL = 8192, BTH = 16384, BTL = 24576;

    const int tid  = threadIdx.x;
    const int w    = tid >> 6, lane = tid & 63;
    const int m0   = blockIdx.y * 128, n0 = blockIdx.x * 128;

    const int wm0 = (w >> 1) * 64, wn0 = (w & 1) * 64;
    const int fr  = lane & 15;     // frag row (A) / col (B)
    const int kg  = lane >> 4;     // k-group 0..3 (8 bf16 each)

    f32x4 acc[4][4] = {};

    // staging geometry: per wave 2 insts/tile, rows w*32 + i*16 + (lane>>2),
    // dest chunk lane&3 (linear), src chunk xor-swizzled.
    const int srow_base = w * 32;
    const int rsub = lane >> 2;
    const int cd   = lane & 3;

    for (int k0 = 0; k0 < K; k0 += 32) {
        __syncthreads();
        #pragma unroll
        for (int i = 0; i < 2; ++i) {
            int row = srow_base + i * 16 + rsub;
            int cs  = cd ^ ((row >> 1) & 3);
            int lo  = (srow_base + i * 16) * 64 + lane * 16;
            size_t ga = (size_t)(m0 + row) * lda + k0 + cs * 8;
            size_t gb = (size_t)(n0 + row) * ldb + k0 + cs * 8;
            gll16(Ah + ga, lds + ATH + lo);
            gll16(Al + ga, lds + ATL + lo);
            gll16(Bh + gb, lds + BTH + lo);
            gll16(Bl + gb, lds + BTL + lo);
        }
        __syncthreads();

        short8v fah[4], fal[4], fbh[4], fbl[4];
        #pragma unroll
        for (int f = 0; f < 4; ++f) {
            int ar = wm0 + f * 16 + fr;
            int ao = ar * 64 + (kg ^ ((ar >> 1) & 3)) * 16;
            fah[f] = *(const short8v*)(lds + ATH + ao);
            fal[f] = *(const short8v*)(lds + ATL + ao);
            int br = wn0 + f * 16 + fr;
            int bo = br * 64 + (kg ^ ((br >> 1) & 3)) * 16;
            fbh[f] = *(const short8v*)(lds + BTH + bo);
            fbl[f] = *(const short8v*)(lds + BTL + bo);
        }
        #pragma unroll
        for (int fm = 0; fm < 4; ++fm)
            #pragma unroll
            for (int fn = 0; fn < 4; ++fn) {
                acc[fm][fn] = __builtin_amdgcn_mfma_f32_16x16x32_bf16(fah[fm], fbh[fn], acc[fm][fn], 0, 0, 0);
                acc[fm][fn] = __builtin_amdgcn_mfma_f32_16x16x32_bf16(fah[fm], fbl[fn], acc[fm][fn], 0, 0, 0);
                acc[fm][fn] = __builtin_amdgcn_mfma_f32_16x16x32_bf16(fal[fm], fbh[fn], acc[fm][fn], 0, 0, 0);
            }
    }

    // epilogue: C/D layout col = lane&15, row = (lane>>4)*4 + j
    #pragma unroll
    for (int fn = 0; fn < 4; ++fn) {
        int col = n0 + wn0 + fn * 16 + fr;
        float bv = bias[col];
        #pragma unroll
        for (int fm = 0; fm < 4; ++fm) {
            int rowb = m0 + wm0 + fm * 16 + kg * 4;
            #pragma unroll
            for (int j = 0; j < 4; ++j) {
                float v = fmaxf(acc[fm][fn][j] + bv, 0.f);
                size_t o = (size_t)(rowb + j) * ldc + col;
                if (epi) {
                    unsigned short h = f2bf(v);
                    Ch[o] = h;
                    Cl[o] = f2bf(v - bf2f(h));
                } else {
                    Cf[o] = v;
                }
            }
        }
    }
}

// ---------------- logits: out = h @ W2 + b2, K=512, N=9 ----------------
__global__ __launch_bounds__(256) void logits_kernel(
    const float* __restrict__ h, const float* __restrict__ W2,
    const float* __restrict__ b2, float* __restrict__ out)
{
    __shared__ float w2s[512 * NCc];
    for (int i = threadIdx.x; i < 512 * NCc; i += 256) w2s[i] = W2[i];
    __syncthreads();

    int wave = threadIdx.x >> 6, lane = threadIdx.x & 63;
    int row = blockIdx.x * 4 + wave;
    const float* hr = h + (size_t)row * 512;

    float p[NCc] = {};
    #pragma unroll
    for (int j = 0; j < 8; ++j) {
        int k = lane + 64 * j;
        float hv = hr[k];
        const float* wrow = &w2s[k * NCc];
        #pragma unroll
        for (int n = 0; n < NCc; ++n) p[n] += hv * wrow[n];
    }
    #pragma unroll
    for (int off = 32; off > 0; off >>= 1) {
        #pragma unroll
        for (int n = 0; n < NCc; ++n) p[n] += __shfl_down(p[n], off);
    }
    if (lane == 0) {
        float* orow = out + (size_t)row * NCc;
        #pragma unroll
        for (int n = 0; n < NCc; ++n) orow[n] = p[n] + b2[n];
    }
}

extern "C" void kernel_launch(void* const* d_in, const int* in_sizes, int n_in,
                              void* d_out, int out_size, void* d_ws, size_t ws_size,
                              hipStream_t stream)
{
    const float* seq   = (const float*)d_in[0];
    const float* feats = (const float*)d_in[1];
    const float* roi   = (const float*)d_in[2];
    const int*   bbox  = (const int*)d_in[3];
    const int*   amask = (const int*)d_in[4];
    const float* Wp = (const float*)d_in[5];
    const float* bp = (const float*)d_in[6];
    const float* Wf = (const float*)d_in[7];
    const float* bf = (const float*)d_in[8];
    const float* W1 = (const float*)d_in[9];
    const float* b1 = (const float*)d_in[10];
    const float* W2 = (const float*)d_in[11];
    const float* b2 = (const float*)d_in[12];
    float* out = (float*)d_out;

    char* ws = (char*)d_ws;
    unsigned short* A_hi  = (unsigned short*)(ws);
    unsigned short* A_lo  = (unsigned short*)(ws + 33554432);
    unsigned short* fu_hi = (unsigned short*)(ws + 67108864);
    unsigned short* fu_lo = (unsigned short*)(ws + 92274688);
    unsigned short* Bf_hi = (unsigned short*)(ws + 117440512);
    unsigned short* Bf_lo = (unsigned short*)(ws + 119013376);
    unsigned short* B1_hi = (unsigned short*)(ws + 120586240);
    unsigned short* B1_lo = (unsigned short*)(ws + 121372672);
    float*          Weq   = (float*)(ws + 122159104);
    float*          beq   = (float*)(ws + 122945536);
    float*          hbuf  = (float*)(ws);              // aliases A_hi/A_lo (dead after fuse)

    weq_beq_kernel<<<257, 768, 0, stream>>>(Wp, bp, Wf, bf, Weq, beq);
    pool_kernel<<<Bb * Rr, 256, 0, stream>>>(seq, roi, bbox, amask, A_hi, A_lo);
    feats_conv<<<Bb * Rr, VDd, 0, stream>>>(feats, A_hi, A_lo);
    // Bf[768][1024] = [ Wf_t^T | Weq^T ]
    tconv_kernel<<<dim3(24, 24), 256, 0, stream>>>(Wf, 768, Bf_hi, Bf_lo, 1024, 0);
    tconv_kernel<<<dim3(8, 24), 256, 0, stream>>>(Weq, 768, Bf_hi, Bf_lo, 1024, 768);
    // B1[512][768] = W1^T
    tconv_kernel<<<dim3(24, 16), 256, 0, stream>>>(W1, 512, B1_hi, B1_lo, 768, 0);

    // fused = relu(A_cat @ B_cat + beq)  [16384,1024]x[1024,768]
    gemm_mfma<<<dim3(768 / 128, 16384 / 128), 256, 0, stream>>>(
        A_hi, A_lo, 1024, Bf_hi, Bf_lo, 1024, 1024, beq, 1,
        fu_hi, fu_lo, nullptr, 768);
    // h = relu(fused @ W1 + b1)  [16384,768]x[768,512]
    gemm_mfma<<<dim3(512 / 128, 16384 / 128), 256, 0, stream>>>(
        fu_hi, fu_lo, 768, B1_hi, B1_lo, 768, 768, b1, 0,
        nullptr, nullptr, hbuf, 512);

    logits_kernel<<<(Bb * Rr) / 4, 256, 0, stream>>>(hbuf, W2, b2, out);
}

// Round 9
// 459.687 us; speedup vs baseline: 1.6258x; 1.0530x over previous
//
#include <hip/hip_runtime.h>
#include <hip/hip_bf16.h>

// LayoutLM w/ visual features — split-bf16 MFMA, 2-phase double-buffered GEMM.
// B=64 S=512 H=768 R=256 VD=256 NC=9
// fuse GEMM: [16384,1024]@[1024,768]; h1 GEMM: [16384,768]@[768,512]
// 3-term split-bf16 (Ah*Bh + Ah*Bl + Al*Bh), fp32 accum.
// R9: T3-min 2-phase (dbuf LDS 64KB, 1 barrier/K-step) + T1 XCD swizzle.
//
// ws layout (bytes): unchanged from R8 (~123 MB).

#define Bb 64
#define Ss 512
#define Hh 768
#define Rr 256
#define VDd 256
#define NCc 9

typedef __attribute__((ext_vector_type(8))) short short8v;  // 8 bf16 = 4 VGPR
typedef __attribute__((ext_vector_type(4))) float f32x4;

__device__ __forceinline__ unsigned short f2bf(float v) {
    __hip_bfloat16 b = __float2bfloat16(v);
    return __builtin_bit_cast(unsigned short, b);
}
__device__ __forceinline__ float bf2f(unsigned short u) {
    return __bfloat162float(__builtin_bit_cast(__hip_bfloat16, u));
}

__device__ __forceinline__ void gll16(const void* g, void* l) {
    __builtin_amdgcn_global_load_lds(
        (const __attribute__((address_space(1))) void*)g,
        (__attribute__((address_space(3))) void*)l, 16, 0, 0);
}

// ---------------- Weq / beq precompute (fp32) ----------------
__global__ __launch_bounds__(768) void weq_beq_kernel(
    const float* __restrict__ Wp, const float* __restrict__ bp,
    const float* __restrict__ Wf, const float* __restrict__ bf,
    float* __restrict__ Weq, float* __restrict__ beq)
{
    int n = threadIdx.x;
    int m = blockIdx.x;
    const float* Wfv = Wf + 768 * 768 + n;   // column n of Wf_v
    float acc = 0.f;
    if (m < 256) {
        const float* a = Wp + m * 768;
        #pragma unroll 4
        for (int k = 0; k < 768; ++k) acc += a[k] * Wfv[(size_t)k * 768];
        Weq[m * 768 + n] = acc;
    } else {
        #pragma unroll 4
        for (int k = 0; k < 768; ++k) acc += bp[k] * Wfv[(size_t)k * 768];
        beq[n] = bf[n] + acc;
    }
}

// ---------------- sparse masked mean pool -> bf16 hi/lo ----------------
__global__ __launch_bounds__(256) void pool_kernel(
    const float* __restrict__ seq,   // [B,S,H]
    const float* __restrict__ roi,   // [B,R,4]
    const int*   __restrict__ bbox,  // [B,S,4]
    const int*   __restrict__ amask, // [B,S]
    unsigned short* __restrict__ ah, // A_hi [16384][1024], cols 0..767
    unsigned short* __restrict__ al)
{
    int br = blockIdx.x;
    int b  = br >> 8;
    int tid = threadIdx.x;
    int wave = tid >> 6, lane = tid & 63;

    float4 rb = reinterpret_cast<const float4*>(roi)[br];

    __shared__ unsigned long long wm[8];
    __shared__ int s_idx[Ss];

    const int4* bb4 = reinterpret_cast<const int4*>(bbox) + (size_t)b * Ss;
    const int*  am  = amask + (size_t)b * Ss;

    for (int it = 0; it < 2; ++it) {
        int s = it * 256 + tid;
        bool pred = false;
        if (s >= 1 && am[s] == 1) {
            int4 tb = bb4[s];
            pred = ((float)tb.x >= rb.x) && ((float)tb.z <= rb.z) &&
                   ((float)tb.y >= rb.y) && ((float)tb.w <= rb.w);
        }
        unsigned long long mk = __ballot(pred);
        if (lane == 0) wm[it * 4 + wave] = mk;
    }
    __syncthreads();

    int pre[8]; int tot = 0;
    #pragma unroll
    for (int c = 0; c < 8; ++c) { pre[c] = tot; tot += __popcll(wm[c]); }

    #pragma unroll
    for (int it = 0; it < 2; ++it) {
        int c = it * 4 + wave;
        unsigned long long mk = wm[c];
        if ((mk >> lane) & 1ull) {
            int pos = pre[c] + __popcll(mk & ((1ull << lane) - 1ull));
            s_idx[pos] = c * 64 + lane;
        }
    }
    __syncthreads();

    float a0 = 0.f, a1 = 0.f, a2 = 0.f;
    for (int i = 0; i < tot; ++i) {
        const float* row = seq + ((size_t)b * Ss + s_idx[i]) * Hh;
        a0 += row[tid];
        a1 += row[tid + 256];
        a2 += row[tid + 512];
    }
    float inv = 1.f / fmaxf((float)tot, 1.f);
    a0 *= inv; a1 *= inv; a2 *= inv;

    size_t o = (size_t)br * 1024;
    unsigned short h0 = f2bf(a0), h1 = f2bf(a1), h2 = f2bf(a2);
    ah[o + tid]       = h0;  al[o + tid]       = f2bf(a0 - bf2f(h0));
    ah[o + tid + 256] = h1;  al[o + tid + 256] = f2bf(a1 - bf2f(h1));
    ah[o + tid + 512] = h2;  al[o + tid + 512] = f2bf(a2 - bf2f(h2));
}

// ---------------- feats -> A_cat cols 768..1023 (bf16 hi/lo) ----------------
__global__ __launch_bounds__(256) void feats_conv(
    const float* __restrict__ f, unsigned short* __restrict__ ah,
    unsigned short* __restrict__ al)
{
    int m = blockIdx.x, c = threadIdx.x;
    float v = f[(size_t)m * VDd + c];
    size_t o = (size_t)m * 1024 + 768 + c;
    unsigned short h = f2bf(v);
    ah[o] = h;
    al[o] = f2bf(v - bf2f(h));
}

// ---------------- transpose + split-convert: dst[n][co+k] = src[k][n] ----------------
__global__ __launch_bounds__(256) void tconv_kernel(
    const float* __restrict__ src, int Ns,
    unsigned short* __restrict__ dh, unsigned short* __restrict__ dl,
    int ldd, int co)
{
    __shared__ float t[32][33];
    int k0 = blockIdx.x * 32, n0 = blockIdx.y * 32;
    int tx = threadIdx.x & 31, ty = threadIdx.x >> 5;
    #pragma unroll
    for (int i = 0; i < 4; ++i)
        t[ty + i * 8][tx] = src[(size_t)(k0 + ty + i * 8) * Ns + n0 + tx];
    __syncthreads();
    #pragma unroll
    for (int i = 0; i < 4; ++i) {
        int n = n0 + ty + i * 8;
        int k = k0 + tx;
        float v = t[tx][ty + i * 8];
        size_t o = (size_t)n * ldd + co + k;
        unsigned short h = f2bf(v);
        dh[o] = h;
        dl[o] = f2bf(v - bf2f(h));
    }
}

// ---------------- split-bf16 MFMA GEMM, 2-phase dbuf ----------------
// 128x128 tile, BK=32, 256 thr (4 waves, 2x2 of 64x64), mfma 16x16x32.
// LDS: 2 buffers x 4 tiles of [128][32] bf16 = 64 KB, XOR-swizzled chunks.
// One barrier per K-step: STAGE(next) || ds_read(cur)+MFMA, then sync
// (compiler emits vmcnt(0) lgkmcnt(0) before s_barrier -> drain overlaps MFMA).
// XCD-bijective block swizzle (nwg % 8 == 0 for both call sites).
__global__ __launch_bounds__(256) void gemm_mfma(
    const unsigned short* __restrict__ Ah, const unsigned short* __restrict__ Al, int lda,
    const unsigned short* __restrict__ Bh, const unsigned short* __restrict__ Bl, int ldb,
    int K, const float* __restrict__ bias, int epi,
    unsigned short* __restrict__ Ch, unsigned short* __restrict__ Cl,
    float* __restrict__ Cf, int ldc)
{
    __shared__ __align__(16) unsigned char lds[65536];
    const int ATH = 0, ATL = 8192, BTH = 16384, BTL = 24576;  // within a 32KB half

    const int tid  = threadIdx.x;
    const int w    = tid >> 6, lane = tid & 63;

    // XCD-bijective swizzle: nwg = gridDim.x*gridDim.y, divisible by 8.
    const int nwg  = gridDim.x * gridDim.y;
    const int cpx  = nwg >> 3;                       // chunk per XCD
    const int orig = blockIdx.y * gridDim.x + blockIdx.x;
    const int swz  = (orig & 7) * cpx + (orig >> 3);
    const int m0   = (swz / gridDim.x) * 128;
    const int n0   = (swz % gridDim.x) * 128;

    const int wm0 = (w >> 1) * 64, wn0 = (w & 1) * 64;
    const int fr  = lane & 15;     // frag row (A) / col (B)
    const int kg  = lane >> 4;     // k-group 0..3 (8 bf16 each)

    f32x4 acc[4][4] = {};

    // staging geometry: per wave 2 insts/array, rows w*32 + i*16 + (lane>>2),
    // dest chunk lane&3 (linear), src chunk xor-swizzled (involution with read).
    const int srow_base = w * 32;
    const int rsub = lane >> 2;
    const int cd   = lane & 3;

    auto STAGE = [&](int bo, int kk) {
        #pragma unroll
        for (int i = 0; i < 2; ++i) {
            int row = srow_base + i * 16 + rsub;
            int cs  = cd ^ ((row >> 1) & 3);
            int lo  = (srow_base + i * 16) * 64 + lane * 16;
            size_t ga = (size_t)(m0 + row) * lda + kk + cs * 8;
            size_t gb = (size_t)(n0 + row) * ldb + kk + cs * 8;
            gll16(Ah + ga, lds + bo + ATH + lo);
            gll16(Al + ga, lds + bo + ATL + lo);
            gll16(Bh + gb, lds + bo + BTH + lo);
            gll16(Bl + gb, lds + bo + BTL + lo);
        }
    };

    const int nt = K >> 5;   // K/32 steps
    STAGE(0, 0);
    __syncthreads();          // vmcnt(0) drain + barrier: buf0 ready

    for (int t = 0; t < nt; ++t) {
        const int cur = (t & 1) << 15;          // 0 or 32768
        if (t + 1 < nt) STAGE(cur ^ 32768, (t + 1) << 5);

        short8v fah[4], fal[4], fbh[4], fbl[4];
        #pragma unroll
        for (int f = 0; f < 4; ++f) {
            int ar = wm0 + f * 16 + fr;
            int ao = ar * 64 + (kg ^ ((ar >> 1) & 3)) * 16;
            fah[f] = *(const short8v*)(lds + cur + ATH + ao);
            fal[f] = *(const short8v*)(lds + cur + ATL + ao);
            int br = wn0 + f * 16 + fr;
            int bo = br * 64 + (kg ^ ((br >> 1) & 3)) * 16;
            fbh[f] = *(const short8v*)(lds + cur + BTH + bo);
            fbl[f] = *(const short8v*)(lds + cur + BTL + bo);
        }
        #pragma unroll
        for (int fm = 0; fm < 4; ++fm)
            #pragma unroll
            for (int fn = 0; fn < 4; ++fn) {
                acc[fm][fn] = __builtin_amdgcn_mfma_f32_16x16x32_bf16(fah[fm], fbh[fn], acc[fm][fn], 0, 0, 0);
                acc[fm][fn] = __builtin_amdgcn_mfma_f32_16x16x32_bf16(fah[fm], fbl[fn], acc[fm][fn], 0, 0, 0);
                acc[fm][fn] = __builtin_amdgcn_mfma_f32_16x16x32_bf16(fal[fm], fbh[fn], acc[fm][fn], 0, 0, 0);
            }
        __syncthreads();      // single barrier/K-step: drains next-buf stage + cur reads
    }

    // epilogue: C/D layout col = lane&15, row = (lane>>4)*4 + j
    #pragma unroll
    for (int fn = 0; fn < 4; ++fn) {
        int col = n0 + wn0 + fn * 16 + fr;
        float bv = bias[col];
        #pragma unroll
        for (int fm = 0; fm < 4; ++fm) {
            int rowb = m0 + wm0 + fm * 16 + kg * 4;
            #pragma unroll
            for (int j = 0; j < 4; ++j) {
                float v = fmaxf(acc[fm][fn][j] + bv, 0.f);
                size_t o = (size_t)(rowb + j) * ldc + col;
                if (epi) {
                    unsigned short h = f2bf(v);
                    Ch[o] = h;
                    Cl[o] = f2bf(v - bf2f(h));
                } else {
                    Cf[o] = v;
                }
            }
        }
    }
}

// ---------------- logits: out = h @ W2 + b2, K=512, N=9 ----------------
__global__ __launch_bounds__(256) void logits_kernel(
    const float* __restrict__ h, const float* __restrict__ W2,
    const float* __restrict__ b2, float* __restrict__ out)
{
    __shared__ float w2s[512 * NCc];
    for (int i = threadIdx.x; i < 512 * NCc; i += 256) w2s[i] = W2[i];
    __syncthreads();

    int wave = threadIdx.x >> 6, lane = threadIdx.x & 63;
    int row = blockIdx.x * 4 + wave;
    const float* hr = h + (size_t)row * 512;

    float p[NCc] = {};
    #pragma unroll
    for (int j = 0; j < 8; ++j) {
        int k = lane + 64 * j;
        float hv = hr[k];
        const float* wrow = &w2s[k * NCc];
        #pragma unroll
        for (int n = 0; n < NCc; ++n) p[n] += hv * wrow[n];
    }
    #pragma unroll
    for (int off = 32; off > 0; off >>= 1) {
        #pragma unroll
        for (int n = 0; n < NCc; ++n) p[n] += __shfl_down(p[n], off);
    }
    if (lane == 0) {
        float* orow = out + (size_t)row * NCc;
        #pragma unroll
        for (int n = 0; n < NCc; ++n) orow[n] = p[n] + b2[n];
    }
}

extern "C" void kernel_launch(void* const* d_in, const int* in_sizes, int n_in,
                              void* d_out, int out_size, void* d_ws, size_t ws_size,
                              hipStream_t stream)
{
    const float* seq   = (const float*)d_in[0];
    const float* feats = (const float*)d_in[1];
    const float* roi   = (const float*)d_in[2];
    const int*   bbox  = (const int*)d_in[3];
    const int*   amask = (const int*)d_in[4];
    const float* Wp = (const float*)d_in[5];
    const float* bp = (const float*)d_in[6];
    const float* Wf = (const float*)d_in[7];
    const float* bf = (const float*)d_in[8];
    const float* W1 = (const float*)d_in[9];
    const float* b1 = (const float*)d_in[10];
    const float* W2 = (const float*)d_in[11];
    const float* b2 = (const float*)d_in[12];
    float* out = (float*)d_out;

    char* ws = (char*)d_ws;
    unsigned short* A_hi  = (unsigned short*)(ws);
    unsigned short* A_lo  = (unsigned short*)(ws + 33554432);
    unsigned short* fu_hi = (unsigned short*)(ws + 67108864);
    unsigned short* fu_lo = (unsigned short*)(ws + 92274688);
    unsigned short* Bf_hi = (unsigned short*)(ws + 117440512);
    unsigned short* Bf_lo = (unsigned short*)(ws + 119013376);
    unsigned short* B1_hi = (unsigned short*)(ws + 120586240);
    unsigned short* B1_lo = (unsigned short*)(ws + 121372672);
    float*          Weq   = (float*)(ws + 122159104);
    float*          beq   = (float*)(ws + 122945536);
    float*          hbuf  = (float*)(ws);              // aliases A_hi/A_lo (dead after fuse)

    weq_beq_kernel<<<257, 768, 0, stream>>>(Wp, bp, Wf, bf, Weq, beq);
    pool_kernel<<<Bb * Rr, 256, 0, stream>>>(seq, roi, bbox, amask, A_hi, A_lo);
    feats_conv<<<Bb * Rr, VDd, 0, stream>>>(feats, A_hi, A_lo);
    // Bf[768][1024] = [ Wf_t^T | Weq^T ]
    tconv_kernel<<<dim3(24, 24), 256, 0, stream>>>(Wf, 768, Bf_hi, Bf_lo, 1024, 0);
    tconv_kernel<<<dim3(8, 24), 256, 0, stream>>>(Weq, 768, Bf_hi, Bf_lo, 1024, 768);
    // B1[512][768] = W1^T
    tconv_kernel<<<dim3(24, 16), 256, 0, stream>>>(W1, 512, B1_hi, B1_lo, 768, 0);

    // fused = relu(A_cat @ B_cat + beq)  [16384,1024]x[1024,768]  (768 blocks, %8==0)
    gemm_mfma<<<dim3(768 / 128, 16384 / 128), 256, 0, stream>>>(
        A_hi, A_lo, 1024, Bf_hi, Bf_lo, 1024, 1024, beq, 1,
        fu_hi, fu_lo, nullptr, 768);
    // h = relu(fused @ W1 + b1)  [16384,768]x[768,512]  (512 blocks, %8==0)
    gemm_mfma<<<dim3(512 / 128, 16384 / 128), 256, 0, stream>>>(
        fu_hi, fu_lo, 768, B1_hi, B1_lo, 768, 768, b1, 0,
        nullptr, nullptr, hbuf, 512);

    logits_kernel<<<(Bb * Rr) / 4, 256, 0, stream>>>(hbuf, W2, b2, out);
}